// Round 11
// baseline (1544.391 us; speedup 1.0000x reference)
//
#include <hip/hip_runtime.h>
#include <hip/hip_bf16.h>

// RelMHAtt: B=4, N=512, H=16, D=64, HS=1024, RS=64, SCALE=0.125
// FULL-PIPELINE DIAGNOSTIC ROUND (R9 technique on all kernels):
// every kernel REP-inflated past the ~160us harness fills so top-5 shows all
// five kernels with exact dur + counters. Reps recompute/rewrite identical
// values (state re-init per rep; buffer reuse race-checked) -> bit-identical
// output. True per-kernel time = dur/REP.
//   prep x24, bias_v3 x4, proj x12, attn x20, out x32.

typedef __bf16 bf16_t;
typedef __bf16 bf16x4 __attribute__((ext_vector_type(4)));
typedef __bf16 bf16x8 __attribute__((ext_vector_type(8)));
typedef float f32x4 __attribute__((ext_vector_type(4)));

#define REP_PREP 24
#define REP_BIAS 4
#define REP_PROJ 12
#define REP_ATTN 20
#define REP_OUT 32

__device__ __forceinline__ f32x4 mfma16(bf16x8 a, bf16x8 b, f32x4 c) {
  return __builtin_amdgcn_mfma_f32_16x16x32_bf16(a, b, c, 0, 0, 0);
}
__device__ __forceinline__ f32x4 zero4() {
  f32x4 z; z[0] = 0.f; z[1] = 0.f; z[2] = 0.f; z[3] = 0.f; return z;
}

#define GLOAD_LDS16(gptr, lptr)                                                   \
  __builtin_amdgcn_global_load_lds(                                               \
      (const __attribute__((address_space(1))) unsigned int*)(gptr),              \
      (__attribute__((address_space(3))) unsigned int*)(lptr), 16, 0, 0)

// ---------------------------------------------------------------------------
__global__ __launch_bounds__(256) void prep_kernel(
    const float* __restrict__ W0, const float* __restrict__ W1,
    const float* __restrict__ W2, const float* __restrict__ W3,
    bf16_t* __restrict__ OutBase,
    const float* __restrict__ q, const float* __restrict__ k, const float* __restrict__ v,
    bf16_t* __restrict__ Qc, bf16_t* __restrict__ Kc, bf16_t* __restrict__ Vc,
    const unsigned int* __restrict__ mw, int* __restrict__ flag) {
  const int tid = threadIdx.x;
  if (blockIdx.x >= 1024) {
    for (int rep = 0; rep < REP_PREP; ++rep) {
      const size_t gid = (size_t)(blockIdx.x - 1024) * 256 + tid;
      const int which = (int)(gid >> 18);
      const size_t off = (gid & 262143) * 8;
      const float* src = which == 0 ? q : which == 1 ? k : v;
      bf16_t* dst = which == 0 ? Qc : which == 1 ? Kc : Vc;
      const float scl = which == 0 ? 0.125f : 1.0f;
      float4 f0 = *(const float4*)(src + off);
      float4 f1 = *(const float4*)(src + off + 4);
      bf16x8 o;
      o[0] = (bf16_t)(f0.x * scl); o[1] = (bf16_t)(f0.y * scl);
      o[2] = (bf16_t)(f0.z * scl); o[3] = (bf16_t)(f0.w * scl);
      o[4] = (bf16_t)(f1.x * scl); o[5] = (bf16_t)(f1.y * scl);
      o[6] = (bf16_t)(f1.z * scl); o[7] = (bf16_t)(f1.w * scl);
      *(bf16x8*)(dst + off) = o;
      __asm__ __volatile__("" ::: "memory");
    }
    return;
  }
  const int wz = blockIdx.x >> 8, wy = (blockIdx.x >> 4) & 15, wx = blockIdx.x & 15;
  const float* W = wz == 0 ? W0 : wz == 1 ? W1 : wz == 2 ? W2 : W3;
  bf16_t* Ot = OutBase + (size_t)wz * 1024 * 1024;
  __shared__ float tile[64][68];
  __shared__ int sflag;
  const bool probe = (blockIdx.x == 0);
  for (int rep = 0; rep < REP_PREP; ++rep) {
    if (probe && tid == 0) sflag = 0;
    const int i0 = wy * 64, j0 = wx * 64;
    const int ri = tid >> 2, rc = (tid & 3) * 16;
    const float* src = W + (size_t)(i0 + ri) * 1024 + j0 + rc;
#pragma unroll
    for (int qq = 0; qq < 4; ++qq) {
      float4 f = *(const float4*)(src + qq * 4);
      *(float4*)(&tile[ri][rc + qq * 4]) = f;
    }
    if (probe) {
      int any = 0;
      for (int i = tid; i < 4096; i += 256) any |= (mw[i] > 1u) ? 1 : 0;
      if (any) atomicOr(&sflag, 1);
    }
    __syncthreads();
    const int wj = tid >> 2, wc = (tid & 3) * 16;
    bf16x8 o0, o1;
#pragma unroll
    for (int s = 0; s < 8; ++s) o0[s] = (bf16_t)tile[wc + s][wj];
#pragma unroll
    for (int s = 0; s < 8; ++s) o1[s] = (bf16_t)tile[wc + 8 + s][wj];
    bf16_t* dst = Ot + (size_t)(j0 + wj) * 1024 + i0 + wc;
    *(bf16x8*)dst = o0;
    *(bf16x8*)(dst + 8) = o1;
    if (probe && tid == 0) *flag = sflag;
    __syncthreads();  // protect tile before next rep's overwrite
    __asm__ __volatile__("" ::: "memory");
  }
}

// ---------------------------------------------------------------------------
__global__ __launch_bounds__(256) void bias_v3(
    const float* __restrict__ rel, const float* __restrict__ Wr,
    const float* __restrict__ br, const void* __restrict__ mask,
    const int* __restrict__ mflag, bf16_t* __restrict__ biasM) {
  __shared__ __align__(16) float relS[2][64 * 64];
  __shared__ __align__(16) bf16_t outS[4][16 * 20];
  const int tid = threadIdx.x, wid = tid >> 6, lane = tid & 63;
  const int lg = lane >> 4, lc = lane & 15;
  const int pair = blockIdx.x;
  const int b = pair >> 9, qrow = pair & 511;
  const int isU8 = *mflag;

  bf16x8 wf[2];
#pragma unroll
  for (int kk = 0; kk < 2; ++kk)
#pragma unroll
    for (int j = 0; j < 8; ++j)
      wf[kk][j] = (bf16_t)Wr[(kk * 32 + lg * 8 + j) * 16 + lc];
  float brv[4];
#pragma unroll
  for (int j = 0; j < 4; ++j) brv[j] = br[lg * 4 + j];

  const float* relblk = rel + (size_t)pair * 32768;
  const size_t mbase = (size_t)b * 262144 + (size_t)qrow * 512;
  bf16_t* outb = biasM + (size_t)b * 16 * 262144 + (size_t)qrow * 512;

  unsigned mbits = 0;
#pragma unroll
  for (int c = 0; c < 8; ++c) {
    const size_t mi = mbase + c * 64 + wid * 16 + lc;
    const bool mb = isU8 ? (((const unsigned char*)mask)[mi] != 0)
                         : (((const int*)mask)[mi] != 0);
    mbits |= (mb ? 1u : 0u) << c;
  }

  const int s_rsub = lane >> 4, s_p = lane & 15;
#define BSTAGE(C, BUF)                                                          \
  do {                                                                          \
    _Pragma("unroll") for (int i = 0; i < 4; ++i) {                             \
      const int r_ = wid * 16 + i * 4 + s_rsub;                                 \
      const float* src_ =                                                       \
          relblk + ((size_t)(C) * 64 + r_) * 64 + ((s_p ^ (r_ & 7)) << 2);      \
      GLOAD_LDS16(src_, &relS[BUF][wid * 1024 + i * 256]);                      \
    }                                                                           \
  } while (0)

  const int h_ = lane >> 2, k4_ = lane & 3;
  for (int rep = 0; rep < REP_BIAS; ++rep) {
    BSTAGE(0, 0);
    for (int c = 0; c < 8; ++c) {
      const int buf = c & 1;
      __syncthreads();
      if (c < 7) BSTAGE(c + 1, buf ^ 1);

      const float* Rb = relS[buf];
      const int rowL = wid * 16 + lc;
      const int x = lc & 7;
      f32x4 acc;
      acc[0] = brv[0]; acc[1] = brv[1]; acc[2] = brv[2]; acc[3] = brv[3];
#pragma unroll
      for (int kk = 0; kk < 2; ++kk) {
        const int c0 = kk * 8 + lg * 2;
        float4 f0 = *(const float4*)(Rb + rowL * 64 + ((c0 ^ x) << 2));
        float4 f1 = *(const float4*)(Rb + rowL * 64 + (((c0 + 1) ^ x) << 2));
        bf16x8 bfr;
        bfr[0] = (bf16_t)f0.x; bfr[1] = (bf16_t)f0.y; bfr[2] = (bf16_t)f0.z; bfr[3] = (bf16_t)f0.w;
        bfr[4] = (bf16_t)f1.x; bfr[5] = (bf16_t)f1.y; bfr[6] = (bf16_t)f1.z; bfr[7] = (bf16_t)f1.w;
        acc = mfma16(wf[kk], bfr, acc);
      }
      const bool mb = (mbits >> c) & 1;
      bf16_t* oS = outS[wid];
#pragma unroll
      for (int j = 0; j < 4; ++j) {
        const float valf = mb ? -1e9f : __logf(fmaxf(acc[j], 1e-6f));
        oS[(lg * 4 + j) * 20 + lc] = (bf16_t)valf;
      }
      bf16x4 ov = *(const bf16x4*)(oS + h_ * 20 + k4_ * 4);
      *(bf16x4*)(outb + (size_t)h_ * 262144 + c * 64 + wid * 16 + k4_ * 4) = ov;
    }
    __syncthreads();  // drain before next rep restages relS[0]
    __asm__ __volatile__("" ::: "memory");
  }
#undef BSTAGE
}

// ---------------------------------------------------------------------------
__global__ __launch_bounds__(256) void proj_gemm2(
    const bf16_t* __restrict__ Aq, const bf16_t* __restrict__ Ak, const bf16_t* __restrict__ Av,
    const bf16_t* __restrict__ Bq, const bf16_t* __restrict__ Bk, const bf16_t* __restrict__ Bv,
    bf16_t* __restrict__ Oq, bf16_t* __restrict__ Ok, bf16_t* __restrict__ Ov) {
  const int z = blockIdx.z;
  const bf16_t* A = (z == 0) ? Aq : (z == 1) ? Ak : Av;
  const bf16_t* Bt = (z == 0) ? Bq : (z == 1) ? Bk : Bv;
  bf16_t* Out = (z == 0) ? Oq : (z == 1) ? Ok : Ov;
  __shared__ __align__(16) bf16_t Asm[128 * 64];
  __shared__ __align__(16) bf16_t Bsm[128 * 64];
  const int tid = threadIdx.x, wid = tid >> 6, lane = tid & 63;
  const int lg = lane >> 4, lc = lane & 15;
  const int m0 = blockIdx.y * 128, n0 = blockIdx.x * 128;
  const int wm = (wid >> 1) * 64, wn = (wid & 1) * 64;
  const int sr = lane >> 3, scch = lane & 7;
  const int srcch = scch ^ sr;
  const bf16_t* Ap[4];
  const bf16_t* Bp[4];
#pragma unroll
  for (int i = 0; i < 4; ++i) {
    const int r = wid * 32 + i * 8 + sr;
    Ap[i] = A + (size_t)(m0 + r) * 1024 + srcch * 8;
    Bp[i] = Bt + (size_t)(n0 + r) * 1024 + srcch * 8;
  }
  for (int rep = 0; rep < REP_PROJ; ++rep) {
    f32x4 acc[4][4];
#pragma unroll
    for (int i = 0; i < 4; ++i)
#pragma unroll
      for (int j = 0; j < 4; ++j) acc[i][j] = zero4();

    for (int k0 = 0; k0 < 1024; k0 += 64) {
#pragma unroll
      for (int i = 0; i < 4; ++i) {
        GLOAD_LDS16(Ap[i] + k0, Asm + (wid * 32 + i * 8) * 64);
        GLOAD_LDS16(Bp[i] + k0, Bsm + (wid * 32 + i * 8) * 64);
      }
      __syncthreads();
#pragma unroll
      for (int kk = 0; kk < 2; ++kk) {
        bf16x8 af[4], bfv[4];
#pragma unroll
        for (int i = 0; i < 4; ++i) {
          const int ar = wm + i * 16 + lc;
          af[i] = *(const bf16x8*)(Asm + ar * 64 + ((kk * 4 + lg) ^ (ar & 7)) * 8);
          const int brr = wn + i * 16 + lc;
          bfv[i] = *(const bf16x8*)(Bsm + brr * 64 + ((kk * 4 + lg) ^ (brr & 7)) * 8);
        }
#pragma unroll
        for (int mi = 0; mi < 4; ++mi)
#pragma unroll
          for (int ni = 0; ni < 4; ++ni) acc[mi][ni] = mfma16(af[mi], bfv[ni], acc[mi][ni]);
      }
      __syncthreads();
    }
#pragma unroll
    for (int mi = 0; mi < 4; ++mi)
#pragma unroll
      for (int ni = 0; ni < 4; ++ni)
#pragma unroll
        for (int j = 0; j < 4; ++j) {
          const int m = m0 + wm + mi * 16 + lg * 4 + j;
          const int col = n0 + wn + ni * 16 + lc;
          const int b = m >> 9, n = m & 511;
          const int h = col >> 6, d = col & 63;
          Out[(((size_t)(b * 16 + h)) * 512 + n) * 64 + d] = (bf16_t)acc[mi][ni][j];
        }
    __asm__ __volatile__("" ::: "memory");
  }
}

// ---------------------------------------------------------------------------
__global__ __launch_bounds__(256) void attn_kernel(
    const bf16_t* __restrict__ Qh, const bf16_t* __restrict__ Kh,
    const bf16_t* __restrict__ Vh, const bf16_t* __restrict__ biasM,
    bf16_t* __restrict__ atted) {
  __shared__ __align__(16) bf16_t Ksm[2][64 * 64];
  __shared__ __align__(16) bf16_t Vtsm[2][64 * 88];
  __shared__ __align__(16) bf16_t Psm[4 * 16 * 64];
  const int tid = threadIdx.x, wid = tid >> 6, lane = tid & 63;
  const int lg = lane >> 4, lc = lane & 15;
  const int bid = blockIdx.x;
  const int qt = bid & 7, h = (bid >> 3) & 15, b = bid >> 7;
  const size_t headoff = (size_t)(b * 16 + h) * 512 * 64;
  const bf16_t* Qb = Qh + headoff;
  const bf16_t* Kb = Kh + headoff;
  const bf16_t* Vb = Vh + headoff;
  const int q0 = qt * 64 + wid * 16;
  const bf16_t* biasb = biasM + ((size_t)(b * 16 + h) * 512 + q0) * 512;

  bf16x8 qf[2];
#pragma unroll
  for (int kk = 0; kk < 2; ++kk)
    qf[kk] = *(const bf16x8*)(Qb + (size_t)(q0 + lc) * 64 + kk * 32 + lg * 8);

  const int krow = tid & 63, kc0 = (tid >> 6) * 2;
  const int vn = tid & 63, vd0 = (tid >> 6) * 16;
  bf16_t* Pw = Psm + wid * 16 * 64;

#define STAGE(T, BUF)                                                          \
  do {                                                                         \
    const int kb_ = (T) * 64;                                                  \
    _Pragma("unroll") for (int ci = 0; ci < 2; ++ci) {                         \
      const int c_ = kc0 + ci;                                                 \
      bf16x8 kv_ = *(const bf16x8*)(Kb + (size_t)(kb_ + krow) * 64 + c_ * 8);  \
      *(bf16x8*)(Ksm[BUF] + krow * 64 + (c_ ^ (krow & 7)) * 8) = kv_;          \
    }                                                                          \
    bf16x8 v0_ = *(const bf16x8*)(Vb + (size_t)(kb_ + vn) * 64 + vd0);         \
    bf16x8 v1_ = *(const bf16x8*)(Vb + (size_t)(kb_ + vn) * 64 + vd0 + 8);     \
    _Pragma("unroll") for (int i = 0; i < 8; ++i)                              \
        Vtsm[BUF][(vd0 + i) * 88 + vn] = v0_[i];                               \
    _Pragma("unroll") for (int i = 0; i < 8; ++i)                              \
        Vtsm[BUF][(vd0 + 8 + i) * 88 + vn] = v1_[i];                           \
  } while (0)

  for (int rep = 0; rep < REP_ATTN; ++rep) {
    f32x4 Oacc[4];
#pragma unroll
    for (int ds = 0; ds < 4; ++ds) Oacc[ds] = zero4();
    float mrun[4], lrun[4];
#pragma unroll
    for (int j = 0; j < 4; ++j) { mrun[j] = -INFINITY; lrun[j] = 0.f; }

    STAGE(0, 0);
    __syncthreads();

    for (int t = 0; t < 8; ++t) {
      const int cur = t & 1;
      if (t < 7) STAGE(t + 1, cur ^ 1);

      f32x4 sacc[4];
#pragma unroll
      for (int quad = 0; quad < 4; ++quad)
#pragma unroll
        for (int j = 0; j < 4; ++j)
          sacc[quad][j] = (float)biasb[(size_t)(lg * 4 + j) * 512 + t * 64 + quad * 16 + lc];

      const bf16_t* Kc = Ksm[cur];
#pragma unroll
      for (int quad = 0; quad < 4; ++quad) {
        const int kr = quad * 16 + lc;
#pragma unroll
        for (int kk = 0; kk < 2; ++kk) {
          bf16x8 kf = *(const bf16x8*)(Kc + kr * 64 + ((kk * 4 + lg) ^ (kr & 7)) * 8);
          sacc[quad] = mfma16(qf[kk], kf, sacc[quad]);
        }
      }

      float p[4][4];
#pragma unroll
      for (int j = 0; j < 4; ++j) {
        float tmax = fmaxf(fmaxf(sacc[0][j], sacc[1][j]), fmaxf(sacc[2][j], sacc[3][j]));
#pragma unroll
        for (int mm = 1; mm < 16; mm <<= 1) tmax = fmaxf(tmax, __shfl_xor(tmax, mm));
        const float mnew = fmaxf(mrun[j], tmax);
        const float sf = __expf(mrun[j] - mnew);
        mrun[j] = mnew;
        lrun[j] *= sf;
#pragma unroll
        for (int ds = 0; ds < 4; ++ds) Oacc[ds][j] *= sf;
        float psum = 0.f;
#pragma unroll
        for (int quad = 0; quad < 4; ++quad) {
          const float pv = __expf(sacc[quad][j] - mnew);
          p[quad][j] = pv;
          psum += pv;
        }
        lrun[j] += psum;
      }

#pragma unroll
      for (int quad = 0; quad < 4; ++quad)
#pragma unroll
        for (int j = 0; j < 4; ++j) {
          const int row = lg * 4 + j, col = quad * 16 + lc;
          Pw[row * 64 + ((col >> 3) ^ (row & 7)) * 8 + (col & 7)] = (bf16_t)p[quad][j];
        }

      const bf16_t* Vc = Vtsm[cur];
#pragma unroll
      for (int kk = 0; kk < 2; ++kk) {
        bf16x8 pf = *(const bf16x8*)(Pw + lc * 64 + ((kk * 4 + lg) ^ (lc & 7)) * 8);
#pragma unroll
        for (int ds = 0; ds < 4; ++ds) {
          bf16x8 vf = *(const bf16x8*)(Vc + (ds * 16 + lc) * 88 + kk * 32 + lg * 8);
          Oacc[ds] = mfma16(pf, vf, Oacc[ds]);
        }
      }
      __syncthreads();
    }

#pragma unroll
    for (int j = 0; j < 4; ++j) {
      float l = lrun[j];
#pragma unroll
      for (int mm = 1; mm < 16; mm <<= 1) l += __shfl_xor(l, mm);
      lrun[j] = 1.0f / l;
    }
#pragma unroll
    for (int ds = 0; ds < 4; ++ds)
#pragma unroll
      for (int j = 0; j < 4; ++j) {
        const int n = q0 + lg * 4 + j;
        const int d = ds * 16 + lc;
        atted[((size_t)b * 512 + n) * 1024 + h * 64 + d] = (bf16_t)(Oacc[ds][j] * lrun[j]);
      }
    __asm__ __volatile__("" ::: "memory");
  }
#undef STAGE
}

// ---------------------------------------------------------------------------
__global__ __launch_bounds__(256) void out_gemm2(
    const bf16_t* __restrict__ A, const bf16_t* __restrict__ Bt, float* __restrict__ Out) {
  __shared__ __align__(16) bf16_t Asm[128 * 64];
  __shared__ __align__(16) bf16_t Bsm[128 * 64];
  const int tid = threadIdx.x, wid = tid >> 6, lane = tid & 63;
  const int lg = lane >> 4, lc = lane & 15;
  const int m0 = blockIdx.y * 128, n0 = blockIdx.x * 128;
  const int wm = (wid >> 1) * 64, wn = (wid & 1) * 64;
  const int sr = lane >> 3, scch = lane & 7;
  const int srcch = scch ^ sr;
  const bf16_t* Ap[4];
  const bf16_t* Bp[4];
#pragma unroll
  for (int i = 0; i < 4; ++i) {
    const int r = wid * 32 + i * 8 + sr;
    Ap[i] = A + (size_t)(m0 + r) * 1024 + srcch * 8;
    Bp[i] = Bt + (size_t)(n0 + r) * 1024 + srcch * 8;
  }
  for (int rep = 0; rep < REP_OUT; ++rep) {
    f32x4 acc[4][4];
#pragma unroll
    for (int i = 0; i < 4; ++i)
#pragma unroll
      for (int j = 0; j < 4; ++j) acc[i][j] = zero4();

    for (int k0 = 0; k0 < 1024; k0 += 64) {
#pragma unroll
      for (int i = 0; i < 4; ++i) {
        GLOAD_LDS16(Ap[i] + k0, Asm + (wid * 32 + i * 8) * 64);
        GLOAD_LDS16(Bp[i] + k0, Bsm + (wid * 32 + i * 8) * 64);
      }
      __syncthreads();
#pragma unroll
      for (int kk = 0; kk < 2; ++kk) {
        bf16x8 af[4], bfv[4];
#pragma unroll
        for (int i = 0; i < 4; ++i) {
          const int ar = wm + i * 16 + lc;
          af[i] = *(const bf16x8*)(Asm + ar * 64 + ((kk * 4 + lg) ^ (ar & 7)) * 8);
          const int brr = wn + i * 16 + lc;
          bfv[i] = *(const bf16x8*)(Bsm + brr * 64 + ((kk * 4 + lg) ^ (brr & 7)) * 8);
        }
#pragma unroll
        for (int mi = 0; mi < 4; ++mi)
#pragma unroll
          for (int ni = 0; ni < 4; ++ni) acc[mi][ni] = mfma16(af[mi], bfv[ni], acc[mi][ni]);
      }
      __syncthreads();
    }
#pragma unroll
    for (int mi = 0; mi < 4; ++mi)
#pragma unroll
      for (int ni = 0; ni < 4; ++ni)
#pragma unroll
        for (int j = 0; j < 4; ++j) {
          const int m = m0 + wm + mi * 16 + lg * 4 + j;
          const int col = n0 + wn + ni * 16 + lc;
          Out[(size_t)m * 1024 + col] = acc[mi][ni][j];
        }
    __asm__ __volatile__("" ::: "memory");
  }
}

// ---------------------------------------------------------------------------
extern "C" void kernel_launch(void* const* d_in, const int* in_sizes, int n_in,
                              void* d_out, int out_size, void* d_ws, size_t ws_size,
                              hipStream_t stream) {
  const float* v = (const float*)d_in[0];
  const float* k = (const float*)d_in[1];
  const float* q = (const float*)d_in[2];
  const void* mask = d_in[3];
  const float* rel = (const float*)d_in[4];
  const float* Wv = (const float*)d_in[5];
  const float* Wk = (const float*)d_in[6];
  const float* Wq = (const float*)d_in[7];
  const float* Wr = (const float*)d_in[8];
  const float* br = (const float*)d_in[9];
  const float* Wm = (const float*)d_in[10];

  char* ws = (char*)d_ws;
  bf16_t* Wt = (bf16_t*)ws;
  bf16_t* Qh = (bf16_t*)(ws + ((size_t)8 << 20));
  bf16_t* Kh = (bf16_t*)(ws + ((size_t)12 << 20));
  bf16_t* Vh = (bf16_t*)(ws + ((size_t)16 << 20));
  bf16_t* biasM = (bf16_t*)(ws + ((size_t)20 << 20));
  bf16_t* atted = (bf16_t*)(ws + ((size_t)52 << 20));
  bf16_t* Qc = (bf16_t*)(ws + ((size_t)56 << 20));
  bf16_t* Kc = (bf16_t*)(ws + ((size_t)60 << 20));
  bf16_t* Vc = (bf16_t*)(ws + ((size_t)64 << 20));
  int* mflag = (int*)(ws + ((size_t)68 << 20));
  bf16_t* Wvt = Wt + 0 * 1048576;
  bf16_t* Wkt = Wt + 1 * 1048576;
  bf16_t* Wqt = Wt + 2 * 1048576;
  bf16_t* Wmt = Wt + 3 * 1048576;

  prep_kernel<<<dim3(4096), 256, 0, stream>>>(Wv, Wk, Wq, Wm, Wt, q, k, v, Qc, Kc, Vc,
                                              (const unsigned int*)mask, mflag);
  bias_v3<<<dim3(2048), 256, 0, stream>>>(rel, Wr, br, mask, mflag, biasM);
  proj_gemm2<<<dim3(8, 16, 3), 256, 0, stream>>>(Qc, Kc, Vc, Wqt, Wkt, Wvt, Qh, Kh, Vh);
  attn_kernel<<<dim3(512), 256, 0, stream>>>(Qh, Kh, Vh, biasM, atted);
  out_gemm2<<<dim3(8, 16), 256, 0, stream>>>(atted, Wmt, (float*)d_out);
}

// Round 12
// 145.882 us; speedup vs baseline: 10.5866x; 10.5866x over previous
//
#include <hip/hip_runtime.h>
#include <hip/hip_bf16.h>

// RelMHAtt: B=4, N=512, H=16, D=64, HS=1024, RS=64, SCALE=0.125
// R12: bias_v4 = barrier-free per-wave streaming (direct reg loads, wave-private
// LDS transpose, coalesced [b][q][h][k] writes). proj/out retiled 128^2 -> 64^2
// for 2-6 blocks/CU (R11 measured out_gemm at 6% occupancy, half the CUs idle).

typedef __bf16 bf16_t;
typedef __bf16 bf16x8 __attribute__((ext_vector_type(8)));
typedef float f32x4 __attribute__((ext_vector_type(4)));

__device__ __forceinline__ f32x4 mfma16(bf16x8 a, bf16x8 b, f32x4 c) {
  return __builtin_amdgcn_mfma_f32_16x16x32_bf16(a, b, c, 0, 0, 0);
}
__device__ __forceinline__ f32x4 zero4() {
  f32x4 z; z[0] = 0.f; z[1] = 0.f; z[2] = 0.f; z[3] = 0.f; return z;
}

#define GLOAD_LDS16(gptr, lptr)                                                   \
  __builtin_amdgcn_global_load_lds(                                               \
      (const __attribute__((address_space(1))) unsigned int*)(gptr),              \
      (__attribute__((address_space(3))) unsigned int*)(lptr), 16, 0, 0)

// ---------------------------------------------------------------------------
// prep: blocks [0,1024) = weight transpose+cast; [1024,4096) = q/k/v cast.
// Block 0 probes mask dtype (u32 view of u8 mask has words>1) -> mflag.
__global__ __launch_bounds__(256) void prep_kernel(
    const float* __restrict__ W0, const float* __restrict__ W1,
    const float* __restrict__ W2, const float* __restrict__ W3,
    bf16_t* __restrict__ OutBase,
    const float* __restrict__ q, const float* __restrict__ k, const float* __restrict__ v,
    bf16_t* __restrict__ Qc, bf16_t* __restrict__ Kc, bf16_t* __restrict__ Vc,
    const unsigned int* __restrict__ mw, int* __restrict__ flag) {
  const int tid = threadIdx.x;
  if (blockIdx.x >= 1024) {
    const size_t gid = (size_t)(blockIdx.x - 1024) * 256 + tid;  // 786432 threads
    const int which = (int)(gid >> 18);
    const size_t off = (gid & 262143) * 8;
    const float* src = which == 0 ? q : which == 1 ? k : v;
    bf16_t* dst = which == 0 ? Qc : which == 1 ? Kc : Vc;
    const float scl = which == 0 ? 0.125f : 1.0f;
    float4 f0 = *(const float4*)(src + off);
    float4 f1 = *(const float4*)(src + off + 4);
    bf16x8 o;
    o[0] = (bf16_t)(f0.x * scl); o[1] = (bf16_t)(f0.y * scl);
    o[2] = (bf16_t)(f0.z * scl); o[3] = (bf16_t)(f0.w * scl);
    o[4] = (bf16_t)(f1.x * scl); o[5] = (bf16_t)(f1.y * scl);
    o[6] = (bf16_t)(f1.z * scl); o[7] = (bf16_t)(f1.w * scl);
    *(bf16x8*)(dst + off) = o;
    return;
  }
  const int wz = blockIdx.x >> 8, wy = (blockIdx.x >> 4) & 15, wx = blockIdx.x & 15;
  const float* W = wz == 0 ? W0 : wz == 1 ? W1 : wz == 2 ? W2 : W3;
  bf16_t* Ot = OutBase + (size_t)wz * 1024 * 1024;
  __shared__ float tile[64][68];
  __shared__ int sflag;
  const bool probe = (blockIdx.x == 0);
  if (probe && tid == 0) sflag = 0;
  const int i0 = wy * 64, j0 = wx * 64;
  const int ri = tid >> 2, rc = (tid & 3) * 16;
  const float* src = W + (size_t)(i0 + ri) * 1024 + j0 + rc;
#pragma unroll
  for (int qq = 0; qq < 4; ++qq) {
    float4 f = *(const float4*)(src + qq * 4);
    *(float4*)(&tile[ri][rc + qq * 4]) = f;
  }
  if (probe) {
    int any = 0;
    for (int i = tid; i < 4096; i += 256) any |= (mw[i] > 1u) ? 1 : 0;
    if (any) atomicOr(&sflag, 1);
  }
  __syncthreads();
  const int wj = tid >> 2, wc = (tid & 3) * 16;
  bf16x8 o0, o1;
#pragma unroll
  for (int s = 0; s < 8; ++s) o0[s] = (bf16_t)tile[wc + s][wj];
#pragma unroll
  for (int s = 0; s < 8; ++s) o1[s] = (bf16_t)tile[wc + 8 + s][wj];
  bf16_t* dst = Ot + (size_t)(j0 + wj) * 1024 + i0 + wc;
  *(bf16x8*)dst = o0;
  *(bf16x8*)(dst + 8) = o1;
  if (probe && tid == 0) *flag = sflag;
}

// ---------------------------------------------------------------------------
// bias_v4: BARRIER-FREE. One wave per (pair, 128-k slice); 2048 blocks x 4 waves
// = 8192 independent waves. Per 16-k iteration: per-lane 32B-contiguous direct
// loads of rel (B-fragment layout native), 2 MFMA, relu/clip/log, wave-private
// LDS transpose. End: coalesced 64B-run stores to biasM[b][q][h][k].
__global__ __launch_bounds__(256) void bias_v4(
    const float* __restrict__ rel, const float* __restrict__ Wr,
    const float* __restrict__ br, const void* __restrict__ mask,
    const int* __restrict__ mflag, bf16_t* __restrict__ biasM) {
  __shared__ __align__(16) bf16_t outS[4][16 * 132];
  const int tid = threadIdx.x, wid = tid >> 6, lane = tid & 63;
  const int lg = lane >> 4, lc = lane & 15;
  const int pair = blockIdx.x;  // b*512 + q
  const int b = pair >> 9;
  const int isU8 = *mflag;

  bf16x8 wf[2];
#pragma unroll
  for (int kk = 0; kk < 2; ++kk)
#pragma unroll
    for (int j = 0; j < 8; ++j)
      wf[kk][j] = (bf16_t)Wr[(kk * 32 + lg * 8 + j) * 16 + lc];  // Wr^T[h=lc][r]
  float brv[4];
#pragma unroll
  for (int j = 0; j < 4; ++j) brv[j] = br[lg * 4 + j];

  const int kbase = wid * 128;  // wave's k-slice
  const float* relw = rel + (size_t)pair * 32768 + (size_t)kbase * 64;
  const size_t mbase = (size_t)b * 262144 + (size_t)(pair & 511) * 512 + kbase;

  // hoisted mask bits: bit it -> k = kbase + it*16 + lc
  unsigned mbits = 0;
#pragma unroll
  for (int it = 0; it < 8; ++it) {
    const size_t mi = mbase + it * 16 + lc;
    const bool mb = isU8 ? (((const unsigned char*)mask)[mi] != 0)
                         : (((const int*)mask)[mi] != 0);
    mbits |= (mb ? 1u : 0u) << it;
  }

  bf16_t* oS = outS[wid];
#pragma unroll 2
  for (int it = 0; it < 8; ++it) {
    const float* rr = relw + (size_t)(it * 16 + lc) * 64 + lg * 8;
    float4 f0 = *(const float4*)(rr);
    float4 f1 = *(const float4*)(rr + 4);
    float4 f2 = *(const float4*)(rr + 32);
    float4 f3 = *(const float4*)(rr + 36);
    bf16x8 bfr0, bfr1;
    bfr0[0] = (bf16_t)f0.x; bfr0[1] = (bf16_t)f0.y; bfr0[2] = (bf16_t)f0.z; bfr0[3] = (bf16_t)f0.w;
    bfr0[4] = (bf16_t)f1.x; bfr0[5] = (bf16_t)f1.y; bfr0[6] = (bf16_t)f1.z; bfr0[7] = (bf16_t)f1.w;
    bfr1[0] = (bf16_t)f2.x; bfr1[1] = (bf16_t)f2.y; bfr1[2] = (bf16_t)f2.z; bfr1[3] = (bf16_t)f2.w;
    bfr1[4] = (bf16_t)f3.x; bfr1[5] = (bf16_t)f3.y; bfr1[6] = (bf16_t)f3.z; bfr1[7] = (bf16_t)f3.w;
    f32x4 acc;
    acc[0] = brv[0]; acc[1] = brv[1]; acc[2] = brv[2]; acc[3] = brv[3];
    acc = mfma16(wf[0], bfr0, acc);
    acc = mfma16(wf[1], bfr1, acc);
    const bool mb = (mbits >> it) & 1;
#pragma unroll
    for (int j = 0; j < 4; ++j) {
      const float valf = mb ? -1e9f : __logf(fmaxf(acc[j], 1e-6f));
      oS[(lg * 4 + j) * 132 + it * 16 + lc] = (bf16_t)valf;  // [h][k]
    }
  }
  // wave-internal transpose read + coalesced store (64B runs, full lines)
  const int h_ = lane >> 2, k8_ = lane & 3;
  bf16_t* outb = biasM + (size_t)pair * 8192 + kbase;  // [b][q][h][k]
#pragma unroll
  for (int u = 0; u < 4; ++u) {
    bf16x8 ov = *(const bf16x8*)(oS + h_ * 132 + u * 32 + k8_ * 8);
    *(bf16x8*)(outb + (size_t)h_ * 512 + u * 32 + k8_ * 8) = ov;
  }
}

// ---------------------------------------------------------------------------
// Projection GEMM, 64x64 tile (R12: more blocks -> 6/CU, hides barrier drain).
// 4 waves as 2x2 of 32x32. Output scattered bf16 into [b][h][n][d].
__global__ __launch_bounds__(256) void proj_gemm3(
    const bf16_t* __restrict__ Aq, const bf16_t* __restrict__ Ak, const bf16_t* __restrict__ Av,
    const bf16_t* __restrict__ Bq, const bf16_t* __restrict__ Bk, const bf16_t* __restrict__ Bv,
    bf16_t* __restrict__ Oq, bf16_t* __restrict__ Ok, bf16_t* __restrict__ Ov) {
  const int z = blockIdx.z;
  const bf16_t* A = (z == 0) ? Aq : (z == 1) ? Ak : Av;
  const bf16_t* Bt = (z == 0) ? Bq : (z == 1) ? Bk : Bv;
  bf16_t* Out = (z == 0) ? Oq : (z == 1) ? Ok : Ov;
  __shared__ __align__(16) bf16_t Asm[64 * 64];
  __shared__ __align__(16) bf16_t Bsm[64 * 64];
  const int tid = threadIdx.x, wid = tid >> 6, lane = tid & 63;
  const int lg = lane >> 4, lc = lane & 15;
  const int m0 = blockIdx.y * 64, n0 = blockIdx.x * 64;
  const int wm = (wid >> 1) * 32, wn = (wid & 1) * 32;
  const int sr = lane >> 3, scch = lane & 7;
  const int srcch = scch ^ sr;
  const bf16_t* Ap[2];
  const bf16_t* Bp[2];
#pragma unroll
  for (int i = 0; i < 2; ++i) {
    const int r = wid * 16 + i * 8 + sr;
    Ap[i] = A + (size_t)(m0 + r) * 1024 + srcch * 8;
    Bp[i] = Bt + (size_t)(n0 + r) * 1024 + srcch * 8;
  }
  f32x4 acc[2][2];
#pragma unroll
  for (int i = 0; i < 2; ++i)
#pragma unroll
    for (int j = 0; j < 2; ++j) acc[i][j] = zero4();

  for (int k0 = 0; k0 < 1024; k0 += 64) {
#pragma unroll
    for (int i = 0; i < 2; ++i) {
      GLOAD_LDS16(Ap[i] + k0, Asm + (wid * 16 + i * 8) * 64);
      GLOAD_LDS16(Bp[i] + k0, Bsm + (wid * 16 + i * 8) * 64);
    }
    __syncthreads();
#pragma unroll
    for (int kk = 0; kk < 2; ++kk) {
      bf16x8 af[2], bfv[2];
#pragma unroll
      for (int i = 0; i < 2; ++i) {
        const int ar = wm + i * 16 + lc;
        af[i] = *(const bf16x8*)(Asm + ar * 64 + ((kk * 4 + lg) ^ (ar & 7)) * 8);
        const int brr = wn + i * 16 + lc;
        bfv[i] = *(const bf16x8*)(Bsm + brr * 64 + ((kk * 4 + lg) ^ (brr & 7)) * 8);
      }
#pragma unroll
      for (int mi = 0; mi < 2; ++mi)
#pragma unroll
        for (int ni = 0; ni < 2; ++ni) acc[mi][ni] = mfma16(af[mi], bfv[ni], acc[mi][ni]);
    }
    __syncthreads();
  }
#pragma unroll
  for (int mi = 0; mi < 2; ++mi)
#pragma unroll
    for (int ni = 0; ni < 2; ++ni)
#pragma unroll
      for (int j = 0; j < 4; ++j) {
        const int m = m0 + wm + mi * 16 + lg * 4 + j;
        const int col = n0 + wn + ni * 16 + lc;
        const int b = m >> 9, n = m & 511;
        const int h = col >> 6, d = col & 63;
        Out[(((size_t)(b * 16 + h)) * 512 + n) * 64 + d] = (bf16_t)acc[mi][ni][j];
      }
}

// ---------------------------------------------------------------------------
// Flash attention (R5 form; biasM layout now [b][q][h][k]).
__global__ __launch_bounds__(256) void attn_kernel(
    const bf16_t* __restrict__ Qh, const bf16_t* __restrict__ Kh,
    const bf16_t* __restrict__ Vh, const bf16_t* __restrict__ biasM,
    bf16_t* __restrict__ atted) {
  __shared__ __align__(16) bf16_t Ksm[2][64 * 64];
  __shared__ __align__(16) bf16_t Vtsm[2][64 * 88];
  __shared__ __align__(16) bf16_t Psm[4 * 16 * 64];
  const int tid = threadIdx.x, wid = tid >> 6, lane = tid & 63;
  const int lg = lane >> 4, lc = lane & 15;
  const int bid = blockIdx.x;
  const int qt = bid & 7, h = (bid >> 3) & 15, b = bid >> 7;
  const size_t headoff = (size_t)(b * 16 + h) * 512 * 64;
  const bf16_t* Qb = Qh + headoff;
  const bf16_t* Kb = Kh + headoff;
  const bf16_t* Vb = Vh + headoff;
  const int q0 = qt * 64 + wid * 16;
  // biasM[b][q][h][k]: base for q = q0
  const bf16_t* biasb = biasM + (((size_t)(b * 512 + q0)) * 16 + h) * 512;

  bf16x8 qf[2];
#pragma unroll
  for (int kk = 0; kk < 2; ++kk)
    qf[kk] = *(const bf16x8*)(Qb + (size_t)(q0 + lc) * 64 + kk * 32 + lg * 8);

  f32x4 Oacc[4];
#pragma unroll
  for (int ds = 0; ds < 4; ++ds) Oacc[ds] = zero4();
  float mrun[4], lrun[4];
#pragma unroll
  for (int j = 0; j < 4; ++j) { mrun[j] = -INFINITY; lrun[j] = 0.f; }

  const int krow = tid & 63, kc0 = (tid >> 6) * 2;
  const int vn = tid & 63, vd0 = (tid >> 6) * 16;
  bf16_t* Pw = Psm + wid * 16 * 64;

#define STAGE(T, BUF)                                                          \
  do {                                                                         \
    const int kb_ = (T) * 64;                                                  \
    _Pragma("unroll") for (int ci = 0; ci < 2; ++ci) {                         \
      const int c_ = kc0 + ci;                                                 \
      bf16x8 kv_ = *(const bf16x8*)(Kb + (size_t)(kb_ + krow) * 64 + c_ * 8);  \
      *(bf16x8*)(Ksm[BUF] + krow * 64 + (c_ ^ (krow & 7)) * 8) = kv_;          \
    }                                                                          \
    bf16x8 v0_ = *(const bf16x8*)(Vb + (size_t)(kb_ + vn) * 64 + vd0);         \
    bf16x8 v1_ = *(const bf16x8*)(Vb + (size_t)(kb_ + vn) * 64 + vd0 + 8);     \
    _Pragma("unroll") for (int i = 0; i < 8; ++i)                              \
        Vtsm[BUF][(vd0 + i) * 88 + vn] = v0_[i];                               \
    _Pragma("unroll") for (int i = 0; i < 8; ++i)                              \
        Vtsm[BUF][(vd0 + 8 + i) * 88 + vn] = v1_[i];                           \
  } while (0)

  STAGE(0, 0);
  __syncthreads();

  for (int t = 0; t < 8; ++t) {
    const int cur = t & 1;
    if (t < 7) STAGE(t + 1, cur ^ 1);

    f32x4 sacc[4];
#pragma unroll
    for (int quad = 0; quad < 4; ++quad)
#pragma unroll
      for (int j = 0; j < 4; ++j)
        sacc[quad][j] =
            (float)biasb[(size_t)(lg * 4 + j) * 8192 + t * 64 + quad * 16 + lc];

    const bf16_t* Kc = Ksm[cur];
#pragma unroll
    for (int quad = 0; quad < 4; ++quad) {
      const int kr = quad * 16 + lc;
#pragma unroll
      for (int kk = 0; kk < 2; ++kk) {
        bf16x8 kf = *(const bf16x8*)(Kc + kr * 64 + ((kk * 4 + lg) ^ (kr & 7)) * 8);
        sacc[quad] = mfma16(qf[kk], kf, sacc[quad]);
      }
    }

    float p[4][4];
#pragma unroll
    for (int j = 0; j < 4; ++j) {
      float tmax = fmaxf(fmaxf(sacc[0][j], sacc[1][j]), fmaxf(sacc[2][j], sacc[3][j]));
#pragma unroll
      for (int mm = 1; mm < 16; mm <<= 1) tmax = fmaxf(tmax, __shfl_xor(tmax, mm));
      const float mnew = fmaxf(mrun[j], tmax);
      const float sf = __expf(mrun[j] - mnew);
      mrun[j] = mnew;
      lrun[j] *= sf;
#pragma unroll
      for (int ds = 0; ds < 4; ++ds) Oacc[ds][j] *= sf;
      float psum = 0.f;
#pragma unroll
      for (int quad = 0; quad < 4; ++quad) {
        const float pv = __expf(sacc[quad][j] - mnew);
        p[quad][j] = pv;
        psum += pv;
      }
      lrun[j] += psum;
    }

#pragma unroll
    for (int quad = 0; quad < 4; ++quad)
#pragma unroll
      for (int j = 0; j < 4; ++j) {
        const int row = lg * 4 + j, col = quad * 16 + lc;
        Pw[row * 64 + ((col >> 3) ^ (row & 7)) * 8 + (col & 7)] = (bf16_t)p[quad][j];
      }

    const bf16_t* Vc = Vtsm[cur];
#pragma unroll
    for (int kk = 0; kk < 2; ++kk) {
      bf16x8 pf = *(const bf16x8*)(Pw + lc * 64 + ((kk * 4 + lg) ^ (lc & 7)) * 8);
#pragma unroll
      for (int ds = 0; ds < 4; ++ds) {
        bf16x8 vf = *(const bf16x8*)(Vc + (ds * 16 + lc) * 88 + kk * 32 + lg * 8);
        Oacc[ds] = mfma16(pf, vf, Oacc[ds]);
      }
    }
    __syncthreads();
  }
#undef STAGE

#pragma unroll
  for (int j = 0; j < 4; ++j) {
    float l = lrun[j];
#pragma unroll
    for (int mm = 1; mm < 16; mm <<= 1) l += __shfl_xor(l, mm);
    lrun[j] = 1.0f / l;
  }
#pragma unroll
  for (int ds = 0; ds < 4; ++ds)
#pragma unroll
    for (int j = 0; j < 4; ++j) {
      const int n = q0 + lg * 4 + j;
      const int d = ds * 16 + lc;
      atted[((size_t)b * 512 + n) * 1024 + h * 64 + d] = (bf16_t)(Oacc[ds][j] * lrun[j]);
    }
}

// ---------------------------------------------------------------------------
// Output GEMM, 64x64 tile: d_out(f32) = atted(bf16) x Wmt(bf16)^T. Grid 512.
__global__ __launch_bounds__(256) void out_gemm3(
    const bf16_t* __restrict__ A, const bf16_t* __restrict__ Bt, float* __restrict__ Out) {
  __shared__ __align__(16) bf16_t Asm[64 * 64];
  __shared__ __align__(16) bf16_t Bsm[64 * 64];
  const int tid = threadIdx.x, wid = tid >> 6, lane = tid & 63;
  const int lg = lane >> 4, lc = lane & 15;
  const int m0 = blockIdx.y * 64, n0 = blockIdx.x * 64;
  const int wm = (wid >> 1) * 32, wn = (wid & 1) * 32;
  const int sr = lane >> 3, scch = lane & 7;
  const int srcch = scch ^ sr;
  const bf16_t* Ap[2];
  const bf16_t* Bp[2];
#pragma unroll
  for (int i = 0; i < 2; ++i) {
    const int r = wid * 16 + i * 8 + sr;
    Ap[i] = A + (size_t)(m0 + r) * 1024 + srcch * 8;
    Bp[i] = Bt + (size_t)(n0 + r) * 1024 + srcch * 8;
  }
  f32x4 acc[2][2];
#pragma unroll
  for (int i = 0; i < 2; ++i)
#pragma unroll
    for (int j = 0; j < 2; ++j) acc[i][j] = zero4();

  for (int k0 = 0; k0 < 1024; k0 += 64) {
#pragma unroll
    for (int i = 0; i < 2; ++i) {
      GLOAD_LDS16(Ap[i] + k0, Asm + (wid * 16 + i * 8) * 64);
      GLOAD_LDS16(Bp[i] + k0, Bsm + (wid * 16 + i * 8) * 64);
    }
    __syncthreads();
#pragma unroll
    for (int kk = 0; kk < 2; ++kk) {
      bf16x8 af[2], bfv[2];
#pragma unroll
      for (int i = 0; i < 2; ++i) {
        const int ar = wm + i * 16 + lc;
        af[i] = *(const bf16x8*)(Asm + ar * 64 + ((kk * 4 + lg) ^ (ar & 7)) * 8);
        const int brr = wn + i * 16 + lc;
        bfv[i] = *(const bf16x8*)(Bsm + brr * 64 + ((kk * 4 + lg) ^ (brr & 7)) * 8);
      }
#pragma unroll
      for (int mi = 0; mi < 2; ++mi)
#pragma unroll
        for (int ni = 0; ni < 2; ++ni) acc[mi][ni] = mfma16(af[mi], bfv[ni], acc[mi][ni]);
    }
    __syncthreads();
  }
#pragma unroll
  for (int mi = 0; mi < 2; ++mi)
#pragma unroll
    for (int ni = 0; ni < 2; ++ni)
#pragma unroll
      for (int j = 0; j < 4; ++j) {
        const int m = m0 + wm + mi * 16 + lg * 4 + j;
        const int col = n0 + wn + ni * 16 + lc;
        Out[(size_t)m * 1024 + col] = acc[mi][ni][j];
      }
}

// ---------------------------------------------------------------------------
extern "C" void kernel_launch(void* const* d_in, const int* in_sizes, int n_in,
                              void* d_out, int out_size, void* d_ws, size_t ws_size,
                              hipStream_t stream) {
  const float* v = (const float*)d_in[0];
  const float* k = (const float*)d_in[1];
  const float* q = (const float*)d_in[2];
  const void* mask = d_in[3];  // dtype (u8 vs i32) resolved on-device
  const float* rel = (const float*)d_in[4];
  const float* Wv = (const float*)d_in[5];
  const float* Wk = (const float*)d_in[6];
  const float* Wq = (const float*)d_in[7];
  const float* Wr = (const float*)d_in[8];
  const float* br = (const float*)d_in[9];
  const float* Wm = (const float*)d_in[10];

  char* ws = (char*)d_ws;
  // layout (MiB): [0,8) Wt x4 (v,k,q,m); [8,12) Qh; [12,16) Kh; [16,20) Vh;
  // [20,52) biasM [b][q][h][k]; [52,56) atted; [56,60) Qc; [60,64) Kc;
  // [64,68) Vc; [68] mflag.
  bf16_t* Wt = (bf16_t*)ws;
  bf16_t* Qh = (bf16_t*)(ws + ((size_t)8 << 20));
  bf16_t* Kh = (bf16_t*)(ws + ((size_t)12 << 20));
  bf16_t* Vh = (bf16_t*)(ws + ((size_t)16 << 20));
  bf16_t* biasM = (bf16_t*)(ws + ((size_t)20 << 20));
  bf16_t* atted = (bf16_t*)(ws + ((size_t)52 << 20));
  bf16_t* Qc = (bf16_t*)(ws + ((size_t)56 << 20));
  bf16_t* Kc = (bf16_t*)(ws + ((size_t)60 << 20));
  bf16_t* Vc = (bf16_t*)(ws + ((size_t)64 << 20));
  int* mflag = (int*)(ws + ((size_t)68 << 20));
  bf16_t* Wvt = Wt + 0 * 1048576;
  bf16_t* Wkt = Wt + 1 * 1048576;
  bf16_t* Wqt = Wt + 2 * 1048576;
  bf16_t* Wmt = Wt + 3 * 1048576;

  prep_kernel<<<dim3(4096), 256, 0, stream>>>(Wv, Wk, Wq, Wm, Wt, q, k, v, Qc, Kc, Vc,
                                              (const unsigned int*)mask, mflag);
  bias_v4<<<dim3(2048), 256, 0, stream>>>(rel, Wr, br, mask, mflag, biasM);
  proj_gemm3<<<dim3(16, 32, 3), 256, 0, stream>>>(Qc, Kc, Vc, Wqt, Wkt, Wvt, Qh, Kh, Vh);
  attn_kernel<<<dim3(512), 256, 0, stream>>>(Qh, Kh, Vh, biasM, atted);
  out_gemm3<<<dim3(16, 32), 256, 0, stream>>>(atted, Wmt, (float*)d_out);
}